// Round 6
// baseline (140.390 us; speedup 1.0000x reference)
//
#include <hip/hip_runtime.h>

typedef float v2f __attribute__((ext_vector_type(2)));

#define NW 64
#define NP 32           // worker pairs
#define MAX_EVALS 12
#define FREEZE_TOL 2e-3f // applied-step freeze; residual after a frozen Newton
                         // step is O(step^2) ~ 1e-5. Bisection lanes <= ~2e-3.

// __launch_bounds__(256,4): VGPR cap ~128 -- without the waves hint the
// allocator squeezed to 52 VGPRs and spilled v[] to scratch (round-2 bug).
__global__ __launch_bounds__(256, 4) void damed_median_kernel(
    const float* __restrict__ y, float* __restrict__ out, int D) {
  int d = blockIdx.x * blockDim.x + threadIdx.x;
  if (d >= D) return;

  // 64 worker values as 32 register pairs (VOP3P operands).
  // y[w][d]: stride-D across w, coalesced across lanes in d.
  v2f v[NP];
  v2f vmin = {3.4e38f, 3.4e38f}, vmax = {-3.4e38f, -3.4e38f}, sum2 = {0.f, 0.f};
#pragma unroll
  for (int p = 0; p < NP; ++p) {
    v2f t;
    t.x = y[(size_t)(2 * p) * (size_t)D + (size_t)d];
    t.y = y[(size_t)(2 * p + 1) * (size_t)D + (size_t)d];
    v[p] = t;
    vmin = __builtin_elementwise_min(vmin, t);
    vmax = __builtin_elementwise_max(vmax, t);
    sum2 += t;
  }
  float xl = fminf(vmin.x, vmin.y);
  float xg = fmaxf(vmax.x, vmax.y);
  float x = (sum2.x + sum2.y) * (1.0f / NW);
  x = fminf(fmaxf(x, xl), xg);

  // A&S 7.1.27: erf(a) = 1 - q(a)^-4, q = 1 + b1 a + b2 a^2 + b3 a^3 + b4 a^4,
  // |err| <= 5e-4, no exp. Exact derivative of the APPROXIMATION:
  // d/da erf_a(a) = 4 q^-5 q'(a), q' = b1 + 2b2 a + 3b3 a^2 + 4b4 a^3 --
  // reuses r = q^-1 and r^4 from the value path; Newton derivative costs
  // one extra 3-term Horner + 2 pk_mul + pk_fma per pair (no transcendental).
  const float B1 = 0.278393f, B2 = 0.230389f, B3 = 0.000972f, B4 = 0.078108f;
  const v2f one2 = {1.f, 1.f};
  const v2f Q1 = {B1, B1}, Q2 = {B2, B2}, Q3 = {B3, B3}, Q4 = {B4, B4};
  const v2f P1 = {B1, B1}, P2 = {2 * B2, 2 * B2};
  const v2f P3 = {3 * B3, 3 * B3}, P4 = {4 * B4, 4 * B4};

  bool frozen = false;
#pragma unroll 1  // one copy of the 64-worker body in I-cache
  for (int e = 0; e < MAX_EVALS; ++e) {
    // fm = sum erf(v-x); fd*4 = |f'| = sum 4 q^-5 q'. 2x2-way split chains.
    v2f fmA = {0.f, 0.f}, fmB = {0.f, 0.f}, fdA = {0.f, 0.f}, fdB = {0.f, 0.f};
    v2f nx = {-x, -x};
#pragma unroll
    for (int p = 0; p < NP; p += 2) {
      v2f tA = v[p] + nx;
      v2f tB = v[p + 1] + nx;
      v2f aA, aB;
      aA.x = __builtin_fabsf(tA.x); aA.y = __builtin_fabsf(tA.y);
      aB.x = __builtin_fabsf(tB.x); aB.y = __builtin_fabsf(tB.y);
      v2f qA = __builtin_elementwise_fma(aA, Q4, Q3);
      v2f qB = __builtin_elementwise_fma(aB, Q4, Q3);
      qA = __builtin_elementwise_fma(aA, qA, Q2);
      qB = __builtin_elementwise_fma(aB, qB, Q2);
      qA = __builtin_elementwise_fma(aA, qA, Q1);
      qB = __builtin_elementwise_fma(aB, qB, Q1);
      qA = __builtin_elementwise_fma(aA, qA, one2);
      qB = __builtin_elementwise_fma(aB, qB, one2);
      v2f dA = __builtin_elementwise_fma(aA, P4, P3);
      v2f dB = __builtin_elementwise_fma(aB, P4, P3);
      dA = __builtin_elementwise_fma(aA, dA, P2);
      dB = __builtin_elementwise_fma(aB, dB, P2);
      dA = __builtin_elementwise_fma(aA, dA, P1);
      dB = __builtin_elementwise_fma(aB, dB, P1);
      v2f rA, rB;
      rA.x = __builtin_amdgcn_rcpf(qA.x); rA.y = __builtin_amdgcn_rcpf(qA.y);
      rB.x = __builtin_amdgcn_rcpf(qB.x); rB.y = __builtin_amdgcn_rcpf(qB.y);
      v2f r2A = rA * rA, r2B = rB * rB;
      v2f r4A = r2A * r2A, r4B = r2B * r2B;
      v2f r5A = r4A * rA, r5B = r4B * rB;
      fdA = __builtin_elementwise_fma(r5A, dA, fdA);
      fdB = __builtin_elementwise_fma(r5B, dB, fdB);
      v2f eA = one2 - r4A;
      v2f eB = one2 - r4B;
      eA.x = __builtin_copysignf(eA.x, tA.x); eA.y = __builtin_copysignf(eA.y, tA.y);
      eB.x = __builtin_copysignf(eB.x, tB.x); eB.y = __builtin_copysignf(eB.y, tB.y);
      fmA += eA; fmB += eB;
    }
    v2f fm2 = fmA + fmB, fd2 = fdA + fdB;
    float fm = fm2.x + fm2.y;
    float fd = 4.0f * (fd2.x + fd2.y);  // |f'| of the approx function, > 0

    // Bracket update by sign of fm (f decreasing in x).
    if (fm > 0.f) xl = x; else xg = x;
    // Newton with per-coordinate slope; NON-STRICT bracket guard (round-1
    // lesson). NaN/inf (fd->0, unreachable with x in bracket) -> bisect.
    float xn = x + fm * __builtin_amdgcn_rcpf(fd);
    bool ok = (xn >= xl) && (xn <= xg);
    float cand = ok ? xn : 0.5f * (xl + xg);
    float st = __builtin_fabsf(cand - x);
    float xnew = frozen ? x : cand;  // frozen lanes do not move
    frozen = frozen || (st <= FREEZE_TOL);
    x = xnew;
    if (__all(frozen)) break;  // wave-uniform exit; deterministic
  }
  out[d] = x;
}

extern "C" void kernel_launch(void* const* d_in, const int* in_sizes, int n_in,
                              void* d_out, int out_size, void* d_ws, size_t ws_size,
                              hipStream_t stream) {
  const float* y = (const float*)d_in[0];
  float* out = (float*)d_out;
  const int D = out_size;  // 2^21 coordinates
  const int threads = 256;
  const int blocks = (D + threads - 1) / threads;
  damed_median_kernel<<<blocks, threads, 0, stream>>>(y, out, D);
}

// Round 7
// 118.891 us; speedup vs baseline: 1.1808x; 1.1808x over previous
//
#include <hip/hip_runtime.h>

typedef float v2f __attribute__((ext_vector_type(2)));

#define NW 64
#define NP 32            // worker pairs
#define MAX_EVALS 10
#define FREEZE_TOL 4.5e-3f
// Freeze fires AFTER the step is applied; a frozen lane's residual is the
// post-step error ~ kappa*st*e_prev (superlinear) ~ <2e-3, not st itself.
// Bisection-fallback lanes (rare) bound at ~tol. Threshold is 1.32e-2.

// __launch_bounds__(256,4): VGPR cap ~128 -- without the waves hint the
// allocator squeezed to 52 VGPRs and spilled v[] to scratch (round-2 bug).
__global__ __launch_bounds__(256, 4) void damed_median_kernel(
    const float* __restrict__ y, float* __restrict__ out, int D) {
  int d = blockIdx.x * blockDim.x + threadIdx.x;
  if (d >= D) return;

  // 64 worker values as 32 register pairs (VOP3P operands).
  // y[w][d]: stride-D across w, coalesced across lanes in d.
  v2f v[NP];
  v2f vmin = {3.4e38f, 3.4e38f}, vmax = {-3.4e38f, -3.4e38f}, sum2 = {0.f, 0.f};
#pragma unroll
  for (int p = 0; p < NP; ++p) {
    v2f t;
    t.x = y[(size_t)(2 * p) * (size_t)D + (size_t)d];
    t.y = y[(size_t)(2 * p + 1) * (size_t)D + (size_t)d];
    v[p] = t;
    vmin = __builtin_elementwise_min(vmin, t);
    vmax = __builtin_elementwise_max(vmax, t);
    sum2 += t;
  }
  float xl = fminf(vmin.x, vmin.y);
  float xg = fmaxf(vmax.x, vmax.y);
  float x = (sum2.x + sum2.y) * (1.0f / NW);
  x = fminf(fmaxf(x, xl), xg);

  // A&S 7.1.27: erf(a) = 1 - q(a)^-4, q = 1 + b1 a + b2 a^2 + b3 a^3 + b4 a^4,
  // |err| <= 5e-4, no exp. Derivative of the approx: 4 q^-5 q'(a) (used ONCE,
  // on eval A only; later evals use secant slope = free).
  const float B1 = 0.278393f, B2 = 0.230389f, B3 = 0.000972f, B4 = 0.078108f;
  const v2f one2 = {1.f, 1.f};
  const v2f Q1 = {B1, B1}, Q2 = {B2, B2}, Q3 = {B3, B3}, Q4 = {B4, B4};
  const v2f P1 = {B1, B1}, P2 = {2 * B2, 2 * B2};
  const v2f P3 = {3 * B3, 3 * B3}, P4 = {4 * B4, 4 * B4};

  // Value-only eval: fm(xc) = sum_w erf(v_w - xc). 9 pk + 4 scalar + 2 trans
  // per pair; 2x2-way split accumulator chains.
  auto evalF = [&](float xc) -> float {
    v2f fmA = {0.f, 0.f}, fmB = {0.f, 0.f};
    v2f nx = {-xc, -xc};
#pragma unroll
    for (int p = 0; p < NP; p += 2) {
      v2f tA = v[p] + nx;
      v2f tB = v[p + 1] + nx;
      v2f aA, aB;
      aA.x = __builtin_fabsf(tA.x); aA.y = __builtin_fabsf(tA.y);
      aB.x = __builtin_fabsf(tB.x); aB.y = __builtin_fabsf(tB.y);
      v2f qA = __builtin_elementwise_fma(aA, Q4, Q3);
      v2f qB = __builtin_elementwise_fma(aB, Q4, Q3);
      qA = __builtin_elementwise_fma(aA, qA, Q2);
      qB = __builtin_elementwise_fma(aB, qB, Q2);
      qA = __builtin_elementwise_fma(aA, qA, Q1);
      qB = __builtin_elementwise_fma(aB, qB, Q1);
      qA = __builtin_elementwise_fma(aA, qA, one2);
      qB = __builtin_elementwise_fma(aB, qB, one2);
      v2f rA, rB;
      rA.x = __builtin_amdgcn_rcpf(qA.x); rA.y = __builtin_amdgcn_rcpf(qA.y);
      rB.x = __builtin_amdgcn_rcpf(qB.x); rB.y = __builtin_amdgcn_rcpf(qB.y);
      rA = rA * rA; rB = rB * rB;   // q^-2
      rA = rA * rA; rB = rB * rB;   // q^-4
      v2f eA = one2 - rA;
      v2f eB = one2 - rB;
      eA.x = __builtin_copysignf(eA.x, tA.x); eA.y = __builtin_copysignf(eA.y, tA.y);
      eB.x = __builtin_copysignf(eB.x, tB.x); eB.y = __builtin_copysignf(eB.y, tB.y);
      fmA += eA; fmB += eB;
    }
    v2f s = fmA + fmB;
    return s.x + s.y;
  };

  // ---- eval A: value + analytic derivative -> one true Newton step. ----
  float fm0, fd0;
  {
    v2f fmA = {0.f, 0.f}, fmB = {0.f, 0.f}, fdA = {0.f, 0.f}, fdB = {0.f, 0.f};
    v2f nx = {-x, -x};
#pragma unroll
    for (int p = 0; p < NP; p += 2) {
      v2f tA = v[p] + nx;
      v2f tB = v[p + 1] + nx;
      v2f aA, aB;
      aA.x = __builtin_fabsf(tA.x); aA.y = __builtin_fabsf(tA.y);
      aB.x = __builtin_fabsf(tB.x); aB.y = __builtin_fabsf(tB.y);
      v2f qA = __builtin_elementwise_fma(aA, Q4, Q3);
      v2f qB = __builtin_elementwise_fma(aB, Q4, Q3);
      qA = __builtin_elementwise_fma(aA, qA, Q2);
      qB = __builtin_elementwise_fma(aB, qB, Q2);
      qA = __builtin_elementwise_fma(aA, qA, Q1);
      qB = __builtin_elementwise_fma(aB, qB, Q1);
      qA = __builtin_elementwise_fma(aA, qA, one2);
      qB = __builtin_elementwise_fma(aB, qB, one2);
      v2f dA = __builtin_elementwise_fma(aA, P4, P3);
      v2f dB = __builtin_elementwise_fma(aB, P4, P3);
      dA = __builtin_elementwise_fma(aA, dA, P2);
      dB = __builtin_elementwise_fma(aB, dB, P2);
      dA = __builtin_elementwise_fma(aA, dA, P1);
      dB = __builtin_elementwise_fma(aB, dB, P1);
      v2f rA, rB;
      rA.x = __builtin_amdgcn_rcpf(qA.x); rA.y = __builtin_amdgcn_rcpf(qA.y);
      rB.x = __builtin_amdgcn_rcpf(qB.x); rB.y = __builtin_amdgcn_rcpf(qB.y);
      v2f r2A = rA * rA, r2B = rB * rB;
      v2f r4A = r2A * r2A, r4B = r2B * r2B;
      v2f r5A = r4A * rA, r5B = r4B * rB;
      fdA = __builtin_elementwise_fma(r5A, dA, fdA);
      fdB = __builtin_elementwise_fma(r5B, dB, fdB);
      v2f eA = one2 - r4A;
      v2f eB = one2 - r4B;
      eA.x = __builtin_copysignf(eA.x, tA.x); eA.y = __builtin_copysignf(eA.y, tA.y);
      eB.x = __builtin_copysignf(eB.x, tB.x); eB.y = __builtin_copysignf(eB.y, tB.y);
      fmA += eA; fmB += eB;
    }
    v2f fm2 = fmA + fmB, fd2 = fdA + fdB;
    fm0 = fm2.x + fm2.y;
    fd0 = 4.0f * (fd2.x + fd2.y);  // |f'| of the approx, strictly > 0
  }
  // f decreasing: fm>0 => root above x.
  if (fm0 > 0.f) xl = x; else xg = x;
  float xn = x + fm0 * __builtin_amdgcn_rcpf(fd0);
  bool ok = (xn >= xl) && (xn <= xg);  // non-strict (round-1 lesson); NaN->bisect
  float cand = ok ? xn : 0.5f * (xl + xg);
  bool frozen = (__builtin_fabsf(cand - x) <= FREEZE_TOL);
  float xprev = x, fmprev = fm0;
  x = cand;

  // ---- secant refinement: derivative comes free from (xprev, fmprev). ----
#pragma unroll 1
  for (int e = 1; e < MAX_EVALS; ++e) {
    if (__all(frozen)) break;  // wave-uniform, deterministic for fixed input
    float fmc = evalF(x);
    if (fmc > 0.f) xl = x; else xg = x;
    float xs = x + fmc * (x - xprev) / (fmprev - fmc);  // secant step
    bool ok2 = (xs >= xl) && (xs <= xg);                // NaN/flat -> bisect
    float cand2 = ok2 ? xs : 0.5f * (xl + xg);
    float st = __builtin_fabsf(cand2 - x);
    float xnew = frozen ? x : cand2;   // frozen lanes do not move
    xprev = frozen ? xprev : x;
    fmprev = frozen ? fmprev : fmc;
    frozen = frozen || (st <= FREEZE_TOL);
    x = xnew;
  }
  out[d] = x;
}

extern "C" void kernel_launch(void* const* d_in, const int* in_sizes, int n_in,
                              void* d_out, int out_size, void* d_ws, size_t ws_size,
                              hipStream_t stream) {
  const float* y = (const float*)d_in[0];
  float* out = (float*)d_out;
  const int D = out_size;  // 2^21 coordinates
  const int threads = 256;
  const int blocks = (D + threads - 1) / threads;
  damed_median_kernel<<<blocks, threads, 0, stream>>>(y, out, D);
}